// Round 14
// baseline (326.090 us; speedup 1.0000x reference)
//
#include <hip/hip_runtime.h>
#include <hip/hip_bf16.h>

// Problem dims (fixed by setup_inputs)
constexpr int kNS = 16384;   // support rows
constexpr int kNQ = 8192;    // query rows
constexpr int kD  = 256;     // feature dim
constexpr int kC  = 64;      // classes

// R29 PASSED (313.0 us, main ~99.6). Tail ~213 us; largest item is k_G:
// last fp32 VALU GEMM (2.15 GF at ~50% VALU ~ 25-30 us). R30: k_G -> MFMA.
// A-operand (Q-mu) bf16 frags emitted by qlogits IN-PLACE into the Gh
// region (each wave reads its group fully to regs before overwriting with
// Gh output); B = Mh (already emitted by newt_fin). Per col-group: LDS
// 16x20 transpose -> coalesced float4 G stores + ushort4 Gh stores + q2p
// accum with vectorized Q/mu reads; q2p direct store (no atomics).
// Gh now bf16(bf16-GEMM); q2p from the SAME accumulators (more consistent).
// Main kernel untouched.

// ---------------- workspace layout (float offsets into d_ws), ~24.4 MB ----
constexpr size_t OFF_PSUM  = 0;          // rnorm[16384]; Ph aliases [0..8192) after paccum
constexpr size_t OFF_XTX   = 16704;      // xtxacc[65536] (zeroed, atomic targets)
constexpr size_t OFF_HIST  = 82240;      // hist 2048 + ssum 1 (zeroed in swzs)
constexpr size_t OFF_SSUM  = 84288;
constexpr size_t OFF_MU    = 100736;
constexpr size_t OFF_COV   = 100992;
constexpr size_t OFF_C     = 166784;     // [1]=gamma
constexpr size_t OFF_Y     = 166800;     // Newton X ping (M fp32)
constexpr size_t OFF_MH    = 166800 + 65536;   // bf16 M frags (32768 float-slots)
constexpr size_t OFF_W     = 166800 + 98304;   // w = M@mu (256 floats)
constexpr size_t OFF_T     = 297872;     // Newton T
constexpr size_t OFF_Y2    = 363408;     // Newton X pong
constexpr size_t OFF_S2    = 560016;     // s2[16384] (direct stores)
constexpr size_t OFF_Q2P   = 576400;     // q2p[8192] (direct stores)
constexpr size_t OFF_PART  = 584592;     // part 8192*16*2; cnt/cpart aliases (proto phase)
constexpr size_t OFF_G     = 846736;     // 8192*256 f32; also ShT / proto partials
constexpr size_t OFF_SH    = 2943888;    // 16384*256 bf16 swizzled
constexpr size_t OFF_GH    = 5041040;    // bf16 frags: Qmh (from qlogits) then Gh (from k_G)

typedef __attribute__((ext_vector_type(8))) short bf16x8;
typedef __attribute__((ext_vector_type(4))) float f32x4;

__device__ __forceinline__ unsigned short f2bf(float f) {
  unsigned int w; __builtin_memcpy(&w, &f, 4);
  unsigned int r = (w + 0x7FFFu + ((w >> 16) & 1u)) >> 16;
  return (unsigned short)r;
}

__device__ __forceinline__ float waveReduceSum(float v) {
#pragma unroll
  for (int off = 32; off > 0; off >>= 1) v += __shfl_xor(v, off);
  return v;
}
__device__ __forceinline__ void fma16(float acc[4][4], float4 a, float4 b) {
  acc[0][0] += a.x*b.x; acc[0][1] += a.x*b.y; acc[0][2] += a.x*b.z; acc[0][3] += a.x*b.w;
  acc[1][0] += a.y*b.x; acc[1][1] += a.y*b.y; acc[1][2] += a.y*b.z; acc[1][3] += a.y*b.w;
  acc[2][0] += a.z*b.x; acc[2][1] += a.z*b.y; acc[2][2] += a.z*b.z; acc[2][3] += a.z*b.w;
  acc[3][0] += a.w*b.x; acc[3][1] += a.w*b.y; acc[3][2] += a.w*b.z; acc[3][3] += a.w*b.w;
}

// async global -> LDS, 16 B per lane
__device__ __forceinline__ void gload_lds16(const void* g, void* l) {
  __builtin_amdgcn_global_load_lds(
      (const __attribute__((address_space(1))) unsigned int*)g,
      (__attribute__((address_space(3))) unsigned int*)l, 16, 0, 0);
}

// fused SF swizzle (Sh + transposed ShT) + row inv-norm + zeroing
__global__ void k_swzs_r29(const float* __restrict__ in, unsigned short* __restrict__ out,
                           unsigned short* __restrict__ outT,
                           float* __restrict__ rnorm, float* __restrict__ ws) {
  int gid = blockIdx.x * 256 + threadIdx.x;
  if (gid < 2049) ws[OFF_HIST + gid] = 0.f;
  else if (gid < 2049 + 8192) ws[OFF_Q2P + (gid - 2049)] = 0.f;
  else if (gid < 2049 + 8192 + 65536) ws[OFF_XTX + (gid - 2049 - 8192)] = 0.f;

  __shared__ float rs[16];
  int g = blockIdx.x, t = threadIdx.x;
  if (t < 16) rs[t] = 0.f;
  __syncthreads();
  int ks = t >> 5;
  float4 va[2], vb[2];
  int rr[2], cc[2];
#pragma unroll
  for (int f = 0; f < 2; ++f) {
    int lane = (2 * t + f) & 63;
    int q = lane >> 4, r = lane & 15;
    rr[f] = r; cc[f] = ks * 32 + q * 8;
    const float* src = &in[(size_t)(g * 16 + r) * kD + cc[f]];
    va[f] = *(const float4*)src;
    vb[f] = *(const float4*)(src + 4);
    float s = va[f].x*va[f].x + va[f].y*va[f].y + va[f].z*va[f].z + va[f].w*va[f].w
            + vb[f].x*vb[f].x + vb[f].y*vb[f].y + vb[f].z*vb[f].z + vb[f].w*vb[f].w;
    atomicAdd(&rs[r], s);
  }
  size_t gbase = (size_t)g * 4096;
#pragma unroll
  for (int f = 0; f < 2; ++f) {
    int lane = (2 * t + f) & 63;
    ushort4 o0, o1;
    o0.x = f2bf(va[f].x); o0.y = f2bf(va[f].y); o0.z = f2bf(va[f].z); o0.w = f2bf(va[f].w);
    o1.x = f2bf(vb[f].x); o1.y = f2bf(vb[f].y); o1.z = f2bf(vb[f].z); o1.w = f2bf(vb[f].w);
    unsigned short* dst = &out[gbase + (size_t)ks * 512 + (size_t)lane * 8];
    *(ushort4*)dst = o0;
    *(ushort4*)(dst + 4) = o1;
    // ShT scatter: [dim>>4][row>>5][(((row>>3)&3)*16 + (dim&15))*8 + (row&7)]
    int row = g * 16 + rr[f];
    size_t rbase = (size_t)(row >> 5) * 512 + (((row >> 3) & 3) * 16) * 8 + (row & 7);
#pragma unroll
    for (int u = 0; u < 8; ++u) {
      int d = cc[f] + u;
      float v = (u < 4) ? ((const float*)&va[f])[u] : ((const float*)&vb[f])[u - 4];
      outT[(size_t)(d >> 4) * 262144 + rbase + (size_t)(d & 15) * 8] = f2bf(v);
    }
  }
  __syncthreads();
  if (t < 16) rnorm[g * 16 + t] = 1.0f / fmaxf(sqrtf(rs[t]), 1e-8f);
}

// xtx via MFMA: grid (16 tiles, 16 K-chunks of 1024 rows); atomic acc.
__global__ void k_xtx_mfma_r29(const unsigned short* __restrict__ ShT,
                               float* __restrict__ xtxacc) {
  int t = threadIdx.x, w = t >> 6, lane = t & 63;
  int a = blockIdx.x >> 2, b = blockIdx.x & 3;
  int chunk = blockIdx.y;
  size_t kb = (size_t)chunk * 32 * 512 + (size_t)lane * 8;
  const unsigned short* A0 = ShT + (size_t)(a * 4 + w) * 262144 + kb;
  const unsigned short* B0 = ShT + (size_t)(b * 4 + 0) * 262144 + kb;
  const unsigned short* B1 = ShT + (size_t)(b * 4 + 1) * 262144 + kb;
  const unsigned short* B2 = ShT + (size_t)(b * 4 + 2) * 262144 + kb;
  const unsigned short* B3 = ShT + (size_t)(b * 4 + 3) * 262144 + kb;
  f32x4 acc0 = {0.f,0.f,0.f,0.f}, acc1 = {0.f,0.f,0.f,0.f};
  f32x4 acc2 = {0.f,0.f,0.f,0.f}, acc3 = {0.f,0.f,0.f,0.f};
#pragma unroll
  for (int ks = 0; ks < 32; ++ks) {
    bf16x8 af = *(const bf16x8*)(A0 + ks * 512);
    acc0 = __builtin_amdgcn_mfma_f32_16x16x32_bf16(af, *(const bf16x8*)(B0 + ks * 512), acc0, 0, 0, 0);
    acc1 = __builtin_amdgcn_mfma_f32_16x16x32_bf16(af, *(const bf16x8*)(B1 + ks * 512), acc1, 0, 0, 0);
    acc2 = __builtin_amdgcn_mfma_f32_16x16x32_bf16(af, *(const bf16x8*)(B2 + ks * 512), acc2, 0, 0, 0);
    acc3 = __builtin_amdgcn_mfma_f32_16x16x32_bf16(af, *(const bf16x8*)(B3 + ks * 512), acc3, 0, 0, 0);
  }
  int r0 = a * 64 + w * 16 + (lane >> 4) * 4;
  int c0 = b * 64 + (lane & 15);
#pragma unroll
  for (int i = 0; i < 4; ++i) {
    atomicAdd(&xtxacc[(size_t)(r0 + i) * kD + c0 +  0], acc0[i]);
    atomicAdd(&xtxacc[(size_t)(r0 + i) * kD + c0 + 16], acc1[i]);
    atomicAdd(&xtxacc[(size_t)(r0 + i) * kD + c0 + 32], acc2[i]);
    atomicAdd(&xtxacc[(size_t)(r0 + i) * kD + c0 + 48], acc3[i]);
  }
}

// ---------------- classification path (atomic-free) ----------------
// thread t owns dim t; LDS acc[64][256]; also accumulates raw colsum.
__global__ void k_paccum_r24(const float* __restrict__ X, const int* __restrict__ lab,
                             const float* __restrict__ rnorm,
                             float* __restrict__ partial, float* __restrict__ cntpart,
                             float* __restrict__ cpart) {
  __shared__ float acc[kC * kD];   // 64 KB
  int t = threadIdx.x, b = blockIdx.x;
  for (int i = t; i < kC * kD; i += 256) acc[i] = 0.f;
  __syncthreads();
  int r0 = b * 128;
  float myCnt = 0.f, csum = 0.f;
  for (int r = 0; r < 128; r += 8) {
    int row = r0 + r;
    int   c0 = lab[row + 0], c1 = lab[row + 1], c2 = lab[row + 2], c3 = lab[row + 3];
    int   c4 = lab[row + 4], c5 = lab[row + 5], c6 = lab[row + 6], c7 = lab[row + 7];
    float n0 = rnorm[row + 0], n1 = rnorm[row + 1], n2 = rnorm[row + 2], n3 = rnorm[row + 3];
    float n4 = rnorm[row + 4], n5 = rnorm[row + 5], n6 = rnorm[row + 6], n7 = rnorm[row + 7];
    float x0 = X[(size_t)(row + 0) * kD + t];
    float x1 = X[(size_t)(row + 1) * kD + t];
    float x2 = X[(size_t)(row + 2) * kD + t];
    float x3 = X[(size_t)(row + 3) * kD + t];
    float x4 = X[(size_t)(row + 4) * kD + t];
    float x5 = X[(size_t)(row + 5) * kD + t];
    float x6 = X[(size_t)(row + 6) * kD + t];
    float x7 = X[(size_t)(row + 7) * kD + t];
    csum += ((x0 + x1) + (x2 + x3)) + ((x4 + x5) + (x6 + x7));
    acc[c0 * kD + t] += x0 * n0;
    acc[c1 * kD + t] += x1 * n1;
    acc[c2 * kD + t] += x2 * n2;
    acc[c3 * kD + t] += x3 * n3;
    acc[c4 * kD + t] += x4 * n4;
    acc[c5 * kD + t] += x5 * n5;
    acc[c6 * kD + t] += x6 * n6;
    acc[c7 * kD + t] += x7 * n7;
    myCnt += (t == c0) ? 1.f : 0.f; myCnt += (t == c1) ? 1.f : 0.f;
    myCnt += (t == c2) ? 1.f : 0.f; myCnt += (t == c3) ? 1.f : 0.f;
    myCnt += (t == c4) ? 1.f : 0.f; myCnt += (t == c5) ? 1.f : 0.f;
    myCnt += (t == c6) ? 1.f : 0.f; myCnt += (t == c7) ? 1.f : 0.f;
  }
  __syncthreads();
  float* pb = partial + (size_t)b * (kC * kD);
  for (int c = 0; c < kC; ++c) pb[c * kD + t] = acc[c * kD + t];
  if (t < kC) cntpart[b * kC + t] = myCnt;
  cpart[(size_t)b * kD + t] = csum;
}

// grid kC+1. Blocks 0..63: per-class reduce + normalize + Ph scatter.
// Block 64: mu from colsum partials.
__global__ void k_proto_fin_r28(const float* __restrict__ partial,
                                const float* __restrict__ cntpart,
                                const float* __restrict__ cpart,
                                unsigned short* __restrict__ Ph,
                                float* __restrict__ mu) {
  int c = blockIdx.x, t = threadIdx.x;
  if (c == kC) {
    float s = 0.f;
    for (int b = 0; b < 128; ++b) s += cpart[(size_t)b * kD + t];
    mu[t] = s * (1.0f / (float)kNS);
    return;
  }
  __shared__ float cs[128];
  __shared__ float wred[4];
  __shared__ float cntS, invS;
  if (t < 128) cs[t] = cntpart[t * kC + c];
  __syncthreads();
  float s = 0.f;
  const float* p = partial + (size_t)c * kD + t;
  for (int b = 0; b < 128; ++b) s += p[(size_t)b * (kC * kD)];
  if (t < 64) {
    float cv = cs[t] + cs[t + 64];
    cv = waveReduceSum(cv);
    if (t == 0) cntS = fmaxf(cv, 1.0f);
  }
  __syncthreads();
  float v = s / cntS;
  float ss = waveReduceSum(v * v);
  if ((t & 63) == 0) wred[t >> 6] = ss;
  __syncthreads();
  if (t == 0) invS = 1.0f / fmaxf(sqrtf(wred[0] + wred[1] + wred[2] + wred[3]), 1e-8f);
  __syncthreads();
  float val = v * invS;
  int g = c >> 4, r = c & 15;
  int ks = t >> 5, q = (t >> 3) & 3, j = t & 7;
  Ph[(size_t)g * 4096 + (size_t)ks * 512 + (size_t)(q * 16 + r) * 8 + j] = f2bf(val);
}

// R30: fused Q-normalize + MFMA logits (blocks 0..511; also emits Qmh =
// bf16 frags of Q-mu into GhQ) AND cov+X1 from xtxacc (blocks 512..767).
__global__ void k_qlogits_r30(const float* __restrict__ Q,
                              const unsigned short* __restrict__ Ph,
                              float* __restrict__ out0,
                              const float* __restrict__ xtxacc,
                              const float* __restrict__ mu,
                              float* __restrict__ cov, float* __restrict__ X1,
                              unsigned short* __restrict__ Qmh) {
  if (blockIdx.x >= 512) {
    int i = blockIdx.x - 512, j = threadIdx.x;
    float v = (xtxacc[(size_t)i * kD + j] - (float)kNS * mu[i] * mu[j]) * (1.0f / (float)(kNS - 1));
    if (i == j) v += 1e-4f;
    cov[(size_t)i * kD + j] = v;
    X1[(size_t)i * kD + j] = (i == j ? 2.0f : 0.0f) - v;
    return;
  }
  __shared__ float rs[16];
  __shared__ alignas(16) unsigned short qtile[16][264];
  int g = blockIdx.x, t = threadIdx.x;
  if (t < 16) rs[t] = 0.f;
  __syncthreads();
  int ks0 = t >> 5;
  float4 va[2], vb[2];
  int rr[2], cc[2];
#pragma unroll
  for (int f = 0; f < 2; ++f) {
    int lane = (2 * t + f) & 63;
    int q8 = lane >> 4, r = lane & 15;
    rr[f] = r; cc[f] = ks0 * 32 + q8 * 8;
    const float* src = &Q[(size_t)(g * 16 + r) * kD + cc[f]];
    va[f] = *(const float4*)src;
    vb[f] = *(const float4*)(src + 4);
    float s = va[f].x*va[f].x + va[f].y*va[f].y + va[f].z*va[f].z + va[f].w*va[f].w
            + vb[f].x*vb[f].x + vb[f].y*vb[f].y + vb[f].z*vb[f].z + vb[f].w*vb[f].w;
    atomicAdd(&rs[r], s);
    // Qmh = bf16(Q - mu) frag scatter (same address pattern as k_swz)
    float4 ma = *(const float4*)&mu[cc[f]];
    float4 mb = *(const float4*)&mu[cc[f] + 4];
    ushort4 h0, h1;
    h0.x = f2bf(va[f].x - ma.x); h0.y = f2bf(va[f].y - ma.y);
    h0.z = f2bf(va[f].z - ma.z); h0.w = f2bf(va[f].w - ma.w);
    h1.x = f2bf(vb[f].x - mb.x); h1.y = f2bf(vb[f].y - mb.y);
    h1.z = f2bf(vb[f].z - mb.z); h1.w = f2bf(vb[f].w - mb.w);
    unsigned short* qd = &Qmh[(size_t)g * 4096 + (size_t)ks0 * 512 + (size_t)lane * 8];
    *(ushort4*)qd = h0;
    *(ushort4*)(qd + 4) = h1;
  }
  __syncthreads();
#pragma unroll
  for (int f = 0; f < 2; ++f) {
    float n = 1.0f / fmaxf(sqrtf(rs[rr[f]]), 1e-8f);
    ushort4 o0, o1;
    o0.x = f2bf(va[f].x * n); o0.y = f2bf(va[f].y * n);
    o0.z = f2bf(va[f].z * n); o0.w = f2bf(va[f].w * n);
    o1.x = f2bf(vb[f].x * n); o1.y = f2bf(vb[f].y * n);
    o1.z = f2bf(vb[f].z * n); o1.w = f2bf(vb[f].w * n);
    unsigned short* dst = &qtile[rr[f]][cc[f]];
    *(ushort4*)dst = o0;
    *(ushort4*)(dst + 4) = o1;
  }
  __syncthreads();
  if (t >= 64) return;

  int lane = t, l15 = lane & 15, quad = lane >> 4;
  bf16x8 afrag[8];
#pragma unroll
  for (int ks = 0; ks < 8; ++ks)
    afrag[ks] = *(const bf16x8*)&qtile[l15][ks * 32 + quad * 8];

  f32x4 acc0 = {0.f,0.f,0.f,0.f}, acc1 = {0.f,0.f,0.f,0.f};
  f32x4 acc2 = {0.f,0.f,0.f,0.f}, acc3 = {0.f,0.f,0.f,0.f};
#pragma unroll
  for (int ks = 0; ks < 8; ++ks) {
    bf16x8 b0 = *(const bf16x8*)&Ph[(size_t)0 * 4096 + ks * 512 + (size_t)lane * 8];
    bf16x8 b1 = *(const bf16x8*)&Ph[(size_t)1 * 4096 + ks * 512 + (size_t)lane * 8];
    bf16x8 b2 = *(const bf16x8*)&Ph[(size_t)2 * 4096 + ks * 512 + (size_t)lane * 8];
    bf16x8 b3 = *(const bf16x8*)&Ph[(size_t)3 * 4096 + ks * 512 + (size_t)lane * 8];
    acc0 = __builtin_amdgcn_mfma_f32_16x16x32_bf16(afrag[ks], b0, acc0, 0, 0, 0);
    acc1 = __builtin_amdgcn_mfma_f32_16x16x32_bf16(afrag[ks], b1, acc1, 0, 0, 0);
    acc2 = __builtin_amdgcn_mfma_f32_16x16x32_bf16(afrag[ks], b2, acc2, 0, 0, 0);
    acc3 = __builtin_amdgcn_mfma_f32_16x16x32_bf16(afrag[ks], b3, acc3, 0, 0, 0);
  }
#pragma unroll
  for (int r = 0; r < 4; ++r) {
    float m = fmaxf(fmaxf(acc0[r], acc1[r]), fmaxf(acc2[r], acc3[r]));
#pragma unroll
    for (int off = 8; off >= 1; off >>= 1) m = fmaxf(m, __shfl_xor(m, off));
    float e = expf(acc0[r] - m) + expf(acc1[r] - m) + expf(acc2[r] - m) + expf(acc3[r] - m);
#pragma unroll
    for (int off = 8; off >= 1; off >>= 1) e += __shfl_xor(e, off);
    float lse = m + logf(e);
    size_t row = (size_t)g * 16 + quad * 4 + r;
    out0[row * kC + 0 * 16 + l15] = acc0[r] - lse;
    out0[row * kC + 1 * 16 + l15] = acc1[r] - lse;
    out0[row * kC + 2 * 16 + l15] = acc2[r] - lse;
    out0[row * kC + 3 * 16 + l15] = acc3[r] - lse;
  }
}

// ---------------- regression path ----------------
// one 256x256 matmul step, 1024 threads (4-way split-k + LDS reduce).
__global__ void __launch_bounds__(1024)
k_newt_mm_r17(const float* __restrict__ A, const float* __restrict__ Xin,
              float* __restrict__ Out, int isT) {
  __shared__ float a_s[256];
  __shared__ float red[3][256];
  int i = blockIdx.x, t = threadIdx.x;
  int j = t & 255, kq = t >> 8;
  if (t < 256) a_s[t] = A[(size_t)i * kD + t];
  __syncthreads();
  int k0 = kq * 64;
  const float* Xp = &Xin[(size_t)k0 * kD + j];
  float s0 = 0.f, s1 = 0.f, s2 = 0.f, s3 = 0.f;
#pragma unroll 4
  for (int k = 0; k < 64; k += 4) {
    s0 = fmaf(a_s[k0 + k + 0], Xp[0 * kD], s0);
    s1 = fmaf(a_s[k0 + k + 1], Xp[1 * kD], s1);
    s2 = fmaf(a_s[k0 + k + 2], Xp[2 * kD], s2);
    s3 = fmaf(a_s[k0 + k + 3], Xp[3 * kD], s3);
    Xp += 4 * kD;
  }
  float s = (s0 + s1) + (s2 + s3);
  if (kq) red[kq - 1][j] = s;
  __syncthreads();
  if (t < 256) {
    float tot = s + red[0][j] + red[1][j] + red[2][j];
    float o = isT ? ((i == j ? 2.0f : 0.0f) - tot) : tot;
    Out[(size_t)i * kD + j] = o;
  }
}

// final Newton step: M = X2 @ T -> X1 fp32 + bf16 Mh frags + w = M@mu
__global__ void __launch_bounds__(1024)
k_newt_fin_r29(const float* __restrict__ A, const float* __restrict__ Xin,
               float* __restrict__ Out, const float* __restrict__ mu,
               unsigned short* __restrict__ Mh, float* __restrict__ wv) {
  __shared__ float a_s[256];
  __shared__ float red[3][256];
  __shared__ float wred[16];
  int i = blockIdx.x, t = threadIdx.x;
  int j = t & 255, kq = t >> 8;
  if (t < 256) a_s[t] = A[(size_t)i * kD + t];
  __syncthreads();
  int k0 = kq * 64;
  const float* Xp = &Xin[(size_t)k0 * kD + j];
  float s0 = 0.f, s1 = 0.f, s2 = 0.f, s3 = 0.f;
#pragma unroll 4
  for (int k = 0; k < 64; k += 4) {
    s0 = fmaf(a_s[k0 + k + 0], Xp[0 * kD], s0);
    s1 = fmaf(a_s[k0 + k + 1], Xp[1 * kD], s1);
    s2 = fmaf(a_s[k0 + k + 2], Xp[2 * kD], s2);
    s3 = fmaf(a_s[k0 + k + 3], Xp[3 * kD], s3);
    Xp += 4 * kD;
  }
  float s = (s0 + s1) + (s2 + s3);
  if (kq) red[kq - 1][j] = s;
  __syncthreads();
  float p = 0.f;
  if (t < 256) {
    float tot = s + red[0][j] + red[1][j] + red[2][j];
    Out[(size_t)i * kD + j] = tot;
    Mh[(size_t)(j >> 4) * 4096 + (size_t)(i >> 5) * 512 +
       (size_t)(((i >> 3) & 3) * 16 + (j & 15)) * 8 + (i & 7)] = f2bf(tot);
    p = tot * mu[j];
  }
  p = waveReduceSum(p);
  if ((t & 63) == 0) wred[t >> 6] = p;
  __syncthreads();
  if (t == 0) {
    float sw = 0.f;
#pragma unroll
    for (int x = 0; x < 16; ++x) sw += wred[x];
    wv[i] = sw;
  }
}

// R30: G = (Q-mu)@M via MFMA. GhQ holds Qmh (input) and is overwritten
// in-place with Gh (each wave reads its whole group to regs first).
// grid 512 x 64 (1 wave per 16-row q-group). Outputs: G fp32 (for median),
// Gh bf16 frags, q2p direct store.
__global__ void __launch_bounds__(64)
k_G_mfma_r30(const float* __restrict__ Q, const float* __restrict__ mu,
             const unsigned short* __restrict__ Mh,
             unsigned short* GhQ,                 // no restrict: in-place
             float* __restrict__ G, float* __restrict__ q2p) {
  __shared__ float tile[16][20];   // pad 20: 16B-aligned rows, 2-way banks
  int lane = threadIdx.x;
  int g = blockIdx.x;
  int l15 = lane & 15, quad = lane >> 4;
  const unsigned short* A0 = GhQ + (size_t)g * 4096 + (size_t)lane * 8;
  bf16x8 af[8];
#pragma unroll
  for (int ks = 0; ks < 8; ++ks) af[ks] = *(const bf16x8*)(A0 + ks * 512);

  int myrow = g * 16 + l15;
  float q2pp = 0.f;
#pragma unroll
  for (int cg = 0; cg < 16; ++cg) {
    const unsigned short* B0 = Mh + (size_t)cg * 4096 + (size_t)lane * 8;
    f32x4 acc = {0.f, 0.f, 0.f, 0.f};
#pragma unroll
    for (int ks = 0; ks < 8; ++ks)
      acc = __builtin_amdgcn_mfma_f32_16x16x32_bf16(af[ks], *(const bf16x8*)(B0 + ks * 512), acc, 0, 0, 0);
    // transpose via LDS: lane holds rows quad*4+i, col l15
#pragma unroll
    for (int i = 0; i < 4; ++i) tile[quad * 4 + i][l15] = acc[i];
    __syncthreads();
    float4 v = *(const float4*)&tile[l15][quad * 4];   // row l15, cols quad*4..+3
    int c0 = cg * 16 + quad * 4;
    *(float4*)&G[(size_t)myrow * kD + c0] = v;
    ushort4 h;
    h.x = f2bf(v.x); h.y = f2bf(v.y); h.z = f2bf(v.z); h.w = f2bf(v.w);
    GhQ[(size_t)g * 4096 + (size_t)(c0 >> 5) * 512 +
        (size_t)(((c0 >> 3) & 3) * 16 + l15) * 8 + (c0 & 7) + 0] = h.x;   // placeholder
    *(ushort4*)&GhQ[(size_t)g * 4096 + (size_t)(c0 >> 5) * 512 +
                    (size_t)(((c0 >> 3) & 3) * 16 + l15) * 8 + (c0 & 7)] = h;
    float4 qv = *(const float4*)&Q[(size_t)myrow * kD + c0];
    float4 m4 = *(const float4*)&mu[c0];
    q2pp += v.x * (qv.x + m4.x) + v.y * (qv.y + m4.y)
          + v.z * (qv.z + m4.z) + v.w * (qv.w + m4.w);
    __syncthreads();   // tile reuse safe for next cg
  }
  q2pp += __shfl_xor(q2pp, 16);
  q2pp += __shfl_xor(q2pp, 32);
  if (quad == 0) q2p[myrow] = q2pp;
}

// s2 via MFMA: s2_r = (S@M)_r.S_r - 2 S_r.w + c0. grid kNS/64, 256 thr.
__global__ void k_s2_mfma_r29(const unsigned short* __restrict__ Sh,
                              const unsigned short* __restrict__ Mh,
                              const float* __restrict__ S,
                              const float* __restrict__ mu,
                              const float* __restrict__ wv,
                              float* __restrict__ s2) {
  int t = threadIdx.x, w = t >> 6, lane = t & 63;
  int rg = blockIdx.x * 4 + w;            // rowgroup of 16
  const unsigned short* A0 = Sh + (size_t)rg * 4096 + (size_t)lane * 8;
  bf16x8 af[8];
#pragma unroll
  for (int ks = 0; ks < 8; ++ks) af[ks] = *(const bf16x8*)(A0 + ks * 512);

  float4 m4 = *(const float4*)&mu[lane * 4];
  float4 w4 = *(const float4*)&wv[lane * 4];
  float c0 = waveReduceSum(m4.x*w4.x + m4.y*w4.y + m4.z*w4.z + m4.w*w4.w);

  float s2p[4] = {0.f, 0.f, 0.f, 0.f};
  int rows0 = rg * 16 + (lane >> 4) * 4;
  int l15 = lane & 15;
#pragma unroll
  for (int cg = 0; cg < 16; ++cg) {
    const unsigned short* B0 = Mh + (size_t)cg * 4096 + (size_t)lane * 8;
    f32x4 acc = {0.f, 0.f, 0.f, 0.f};
#pragma unroll
    for (int ks = 0; ks < 8; ++ks)
      acc = __builtin_amdgcn_mfma_f32_16x16x32_bf16(af[ks], *(const bf16x8*)(B0 + ks * 512), acc, 0, 0, 0);
    int col = cg * 16 + l15;
    float wc = wv[col];
#pragma unroll
    for (int i = 0; i < 4; ++i) {
      float sv = S[(size_t)(rows0 + i) * kD + col];
      s2p[i] += acc[i] * sv - 2.0f * sv * wc;
    }
  }
#pragma unroll
  for (int off = 8; off >= 1; off >>= 1)
#pragma unroll
    for (int i = 0; i < 4; ++i) s2p[i] += __shfl_xor(s2p[i], off);
  if (l15 == 0) {
#pragma unroll
    for (int i = 0; i < 4; ++i) s2[rows0 + i] = s2p[i] + c0;
  }
}

// GEMM-tiled sampled-median histogram (s-sample stride 16, grid (16,16))
__global__ void k_median_r27(const float* __restrict__ G, const float* __restrict__ S,
                             const float* __restrict__ q2p, const float* __restrict__ s2,
                             unsigned int* __restrict__ hist, float* __restrict__ ssum) {
  __shared__ alignas(16) float As[16][68];
  __shared__ alignas(16) float Bs[16][68];
  __shared__ unsigned int h[2048];
  __shared__ float fred[4];
  int t = threadIdx.x, tx = t & 15, ty = t >> 4;
  int stile = blockIdx.x, qtile = blockIdx.y;
  for (int i = t; i < 2048; i += 256) h[i] = 0u;

  float acc[4][4] = {};
  for (int k0 = 0; k0 < 256; k0 += 16) {
    __syncthreads();
    {
      int kk = t & 15, m0 = t >> 4;
#pragma unroll
      for (int p = 0; p < 4; ++p) {
        int m = m0 + p * 16;
        As[kk][m] = G[(size_t)((qtile * 64 + m) * 8) * kD + k0 + kk];
        Bs[kk][m] = S[(size_t)((stile * 64 + m) * 16) * kD + k0 + kk];
      }
    }
    __syncthreads();
#pragma unroll
    for (int k = 0; k < 16; ++k) {
      float4 a = *(const float4*)&As[k][ty * 4];
      float4 b = *(const float4*)&Bs[k][tx * 4];
      fma16(acc, a, b);
    }
  }
  float fsum = 0.f;
#pragma unroll
  for (int r = 0; r < 4; ++r) {
    int qi = (qtile * 64 + ty * 4 + r) * 8;
    float q2v = q2p[qi];
#pragma unroll
    for (int c = 0; c < 4; ++c) {
      int sj = (stile * 64 + tx * 4 + c) * 16;
      float d2 = fmaxf(q2v + s2[sj] - 2.0f * acc[r][c], 0.0f);
      fsum += d2;
      int bin = (int)(d2 * 2.0f);
      bin = bin > 2047 ? 2047 : bin;
      atomicAdd(&h[bin], 1u);
    }
  }
  float wsum = waveReduceSum(fsum);
  if ((t & 63) == 0) fred[t >> 6] = wsum;
  __syncthreads();
  if (t == 0) atomicAdd(ssum, fred[0] + fred[1] + fred[2] + fred[3]);
  for (int i = t; i < 2048; i += 256)
    if (h[i]) atomicAdd(&hist[i], h[i]);
}

// Parallel median + gamma: 256 threads x 8 bins, LDS scan.
__global__ void k_gamma_r16(const unsigned int* __restrict__ hist,
                            const float* __restrict__ ssum, float* __restrict__ gptr) {
  __shared__ unsigned int ps[256];
  __shared__ float v0s, v1s;
  int t = threadIdx.x;
  unsigned int mine[8];
  unsigned int c = 0;
#pragma unroll
  for (int j = 0; j < 8; ++j) { mine[j] = hist[t * 8 + j]; c += mine[j]; }
  ps[t] = c;
  __syncthreads();
  for (int off = 1; off < 256; off <<= 1) {
    unsigned int v = (t >= off) ? ps[t - off] : 0u;
    __syncthreads();
    ps[t] += v;
    __syncthreads();
  }
  unsigned int total = ps[255];
  unsigned int before = ps[t] - c;
  if (t == 0) { v0s = 0.f; v1s = 0.f; }
  __syncthreads();
  unsigned int rr0 = (total - 1) / 2, rr1 = total / 2;
  unsigned int cum = before;
#pragma unroll
  for (int j = 0; j < 8; ++j) {
    unsigned int cc = mine[j];
    if (cc > 0) {
      int bin = t * 8 + j;
      if (cum <= rr0 && rr0 < cum + cc) {
        float frac = (float)(rr0 - cum) + 0.5f;
        v0s = ((float)bin + frac / (float)cc) * 0.5f;
      }
      if (cum <= rr1 && rr1 < cum + cc) {
        float frac = (float)(rr1 - cum) + 0.5f;
        v1s = ((float)bin + frac / (float)cc) * 0.5f;
      }
    }
    cum += cc;
  }
  __syncthreads();
  if (t == 0) {
    float med = 0.5f * (v0s + v1s);
    float mean = (total > 0) ? (ssum[0] / (float)total) : 1.0f;
    float g = (med > 0.f) ? 1.0f / (med + 1e-6f) : 1.0f / (mean + 1e-6f);
    gptr[0] = g;
  }
}

// MAIN (MFMA, dbuf prefetch, grid (64,16), 1024 blocks all-resident):
__global__ void __launch_bounds__(256, 4)
PrototypicalHead_6210522710389_kernel(
    const unsigned short* __restrict__ Gh, const unsigned short* __restrict__ Sh,
    const float* __restrict__ q2p, const float* __restrict__ s2,
    const float* __restrict__ svals, const float* __restrict__ gptr,
    float* __restrict__ part) {
  __shared__ unsigned short Bs[2][8192];   // 2 x 16 KB
  int t = threadIdx.x;
  int w = t >> 6, lane = t & 63;
  int l15 = lane & 15, quad = lane >> 4;
  int qt = blockIdx.x, sc = blockIdx.y;
  int qbase = qt * 128;
  float gamma = gptr[0];
  const float LOG2E = 1.44269504f;
  float c2 = 2.0f * gamma * LOG2E;       // exp2 folding: e^{-g*d2} = 2^{c2*a + cq + cs}

  size_t agrp = (size_t)(qt * 8 + w * 2) * 4096;
  bf16x8 afrag[2][8];
#pragma unroll
  for (int s = 0; s < 2; ++s)
#pragma unroll
    for (int ks = 0; ks < 8; ++ks)
      afrag[s][ks] = *(const bf16x8*)&Gh[agrp + (size_t)s * 4096 + (size_t)ks * 512 + (size_t)lane * 8];

  float cqv[2][4];
#pragma unroll
  for (int s = 0; s < 2; ++s)
#pragma unroll
    for (int r = 0; r < 4; ++r)
      cqv[s][r] = -gamma * LOG2E * q2p[qbase + w * 32 + s * 16 + quad * 4 + r];

  float dAcc[2][4] = {}, nAcc[2][4] = {};

  const char* sbase_ptr = (const char*)&Sh[(size_t)(sc * 64) * 4096];
#pragma unroll
  for (int i = 0; i < 4; ++i) {
    int c = i * 256 + t;
    gload_lds16(sbase_ptr + (size_t)c * 16, (char*)&Bs[0][0] + (size_t)c * 16);
  }
  __syncthreads();

  for (int st = 0; st < 32; ++st) {
    int cur = st & 1;
    if (st + 1 < 32) {
      const char* src = sbase_ptr + (size_t)(st + 1) * 16384;
      char* dst = (char*)&Bs[cur ^ 1][0];
#pragma unroll
      for (int i = 0; i < 4; ++i) {
        int c = i * 256 + t;
        gload_lds16(src + (size_t)c * 16, dst + (size_t)c * 16);
      }
    }

    f32x4 acc[2][2];
#pragma unroll
    for (int s = 0; s < 2; ++s)
#pragma unroll
      for (int nt = 0; nt < 2; ++nt)
        acc[s][nt] = (f32x4){0.f, 0.f, 0.f, 0.f};

    const unsigned short* B0 = &Bs[cur][lane * 8];
    __builtin_amdgcn_s_setprio(1);
#pragma unroll
    for (int ks = 0; ks < 8; ++ks) {
      bf16x8 f0 = *(const bf16x8*)(B0 + ks * 512);
      bf16x8 f1 = *(const bf16x8*)(B0 + 4096 + ks * 512);
      acc[0][0] = __builtin_amdgcn_mfma_f32_16x16x32_bf16(afrag[0][ks], f0, acc[0][0], 0, 0, 0);
      acc[1][0] = __builtin_amdgcn_mfma_f32_16x16x32_bf16(afrag[1][ks], f0, acc[1][0], 0, 0, 0);
      acc[0][1] = __builtin_amdgcn_mfma_f32_16x16x32_bf16(afrag[0][ks], f1, acc[0][1], 0, 0, 0);
      acc[1][1] = __builtin_amdgcn_mfma_f32_16x16x32_bf16(afrag[1][ks], f1, acc[1][1], 0, 0, 0);
    }
    __builtin_amdgcn_s_setprio(0);

    int sbase = sc * 1024 + st * 32;
#pragma unroll
    for (int nt = 0; nt < 2; ++nt) {
      int scol = sbase + nt * 16 + l15;
      float cs = -gamma * LOG2E * s2[scol];
      float sv = svals[scol];
#pragma unroll
      for (int s = 0; s < 2; ++s)
#pragma unroll
        for (int r = 0; r < 4; ++r) {
          float ex = exp2f(fminf(fmaf(c2, acc[s][nt][r], cqv[s][r] + cs), 0.0f));
          dAcc[s][r] += ex;
          nAcc[s][r] = fmaf(ex, sv, nAcc[s][r]);
        }
    }
    __syncthreads();
  }
#pragma unroll
  for (int off = 8; off >= 1; off >>= 1)
#pragma unroll
    for (int s = 0; s < 2; ++s)
#pragma unroll
      for (int r = 0; r < 4; ++r) {
        dAcc[s][r] += __shfl_xor(dAcc[s][r], off);
        nAcc[s][r] += __shfl_xor(nAcc[s][r], off);
      }
  if (l15 == 0) {
#pragma unroll
    for (int s = 0; s < 2; ++s)
#pragma unroll
      for (int r = 0; r < 4; ++r) {
        size_t q = (size_t)qbase + w * 32 + s * 16 + quad * 4 + r;
        part[(q * 16 + sc) * 2 + 0] = dAcc[s][r];
        part[(q * 16 + sc) * 2 + 1] = nAcc[s][r];
      }
  }
}

__global__ void k_final_r16(const float* __restrict__ part, float* __restrict__ out1) {
  int q = blockIdx.x * 256 + threadIdx.x;
  const float* p = part + (size_t)q * 32;
  float d = 0.f, n = 0.f;
#pragma unroll
  for (int i = 0; i < 16; ++i) { d += p[2 * i]; n += p[2 * i + 1]; }
  out1[q] = n / d;
}

extern "C" void kernel_launch(void* const* d_in, const int* in_sizes, int n_in,
                              void* d_out, int out_size, void* d_ws, size_t ws_size,
                              hipStream_t stream) {
  (void)in_sizes; (void)n_in; (void)out_size; (void)ws_size;
  const float* SF = (const float*)d_in[0];   // fp32
  const int*   SL = (const int*)d_in[1];     // int32
  const float* SV = (const float*)d_in[2];   // fp32
  const float* QF = (const float*)d_in[3];   // fp32

  float* ws = (float*)d_ws;
  float* rnorm = ws + OFF_PSUM;
  float* xtxacc = ws + OFF_XTX;
  unsigned int* hist = (unsigned int*)(ws + OFF_HIST);
  float* ssum  = ws + OFF_SSUM;
  float* mu    = ws + OFF_MU;
  float* cov   = ws + OFF_COV;
  float* gptr  = ws + OFF_C + 1;
  float* X1 = ws + OFF_Y;  float* T = ws + OFF_T;  float* X2 = ws + OFF_Y2;
  unsigned short* Mh = (unsigned short*)(ws + OFF_MH);
  float* wv = ws + OFF_W;
  float* s2 = ws + OFF_S2; float* q2p = ws + OFF_Q2P;
  float* part = ws + OFF_PART;
  float* G = ws + OFF_G;
  unsigned short* Sh = (unsigned short*)(ws + OFF_SH);
  unsigned short* GhQ = (unsigned short*)(ws + OFF_GH);  // Qmh then Gh (in-place)
  // aliases (lifetimes end before overwriters run):
  unsigned short* ShT = (unsigned short*)G;        // transposed S frags (dead after xtx)
  float* pppart  = G;                              // proto partials (after xtx, dead after proto_fin)
  float* cntpart = part;                           // counts [128*64]
  float* cpart   = part + 8192;                    // colsum partials [128*256]
  unsigned short* Ph = (unsigned short*)(ws + OFF_PSUM);  // proto frags (rnorm dead after paccum)

  float* out0 = (float*)d_out;                   // f32 log_probs [8192 x 64]
  float* out1 = out0 + (size_t)kNQ * kC;         // f32 predictions [8192]

  // fused: zeroing + Sh + ShT + row inv-norms
  k_swzs_r29<<<kNS / 16, 256, 0, stream>>>(SF, Sh, ShT, rnorm, ws);

  // xtx via MFMA (reads ShT in G region; must precede paccum)
  k_xtx_mfma_r29<<<dim3(16, 16), 256, 0, stream>>>(ShT, xtxacc);

  // classification; paccum also emits colsum partials; proto_fin also does mu
  k_paccum_r24<<<128, 256, 0, stream>>>(SF, SL, rnorm, pppart, cntpart, cpart);
  k_proto_fin_r28<<<kC + 1, 256, 0, stream>>>(pppart, cntpart, cpart, Ph, mu);
  // qlogits (blocks 0..511, also emits Qmh) + cov & X1 (blocks 512..767)
  k_qlogits_r30<<<kNQ / 16 + 256, 256, 0, stream>>>(QF, Ph, out0, xtxacc, mu, cov, X1, GhQ);

  // Newton inverse: X1 = 2I - cov, then 2 iterations; final emits Mh + w
  k_newt_mm_r17<<<256, 1024, 0, stream>>>(cov, X1, T, 1);
  k_newt_mm_r17<<<256, 1024, 0, stream>>>(X1, T, X2, 0);
  k_newt_mm_r17<<<256, 1024, 0, stream>>>(cov, X2, T, 1);
  k_newt_fin_r29<<<256, 1024, 0, stream>>>(X2, T, X1, mu, Mh, wv);

  // G = (Q-mu)@M via MFMA (Qmh in GhQ -> overwritten with Gh); G fp32 + q2p
  k_G_mfma_r30<<<kNQ / 16, 64, 0, stream>>>(QF, mu, Mh, GhQ, G, q2p);
  // s2 via MFMA (raw Sh x Mh, direct stores)
  k_s2_mfma_r29<<<kNS / 64, 256, 0, stream>>>(Sh, Mh, SF, mu, wv, s2);

  // sampled median -> gamma (1M samples: q stride 8, s stride 16)
  k_median_r27<<<dim3(16, 16), 256, 0, stream>>>(G, SF, q2p, s2, hist, ssum);
  k_gamma_r16<<<1, 256, 0, stream>>>(hist, ssum, gptr);

  // MFMA fused cdist^2 + softmax numer/denom, then finalize
  PrototypicalHead_6210522710389_kernel<<<dim3(64, 16), 256, 0, stream>>>(
      GhQ, Sh, q2p, s2, SV, gptr, part);
  k_final_r16<<<kNQ / 256, 256, 0, stream>>>(part, out1);
}